// Round 3
// baseline (1764.255 us; speedup 1.0000x reference)
//
#include <hip/hip_runtime.h>
#include <hip/hip_bf16.h>

// SRNN text encoder, restructured (all device inputs/outputs are FP32):
//   Phase 0: convert Wih_f/Wih_b/Whh_f/Whh_b/Wout -> bf16 in ws; gather+convert
//            the 256 used embedding rows (Xemb).
//   Phase 1: Gx[dir][b*32+t][2048] = Xemb @ Wih^T + (bih+bhh)   (fp32) -- its
//            kernel-launch boundary doubles as the one full device sync.
//   Phase 2 (R6): ONE persistent cooperative kernel for all 32 recurrence
//            steps, but with PER-GROUP flag barriers instead of grid.sync().
//            R5's cg::grid.sync() measured ~34 us/step (rec=1094 us,
//            MfmaUtil 0.7%). H rows are private to the 16 blocks sharing
//            (x,dir); C/S/Apack are block-private; Gx is read-only. So only
//            a 16-block barrier is needed: monotone per-block flags,
//            release-store + acquire-spin (lanes 0..15), s_sleep poll.
//            Whh fragments register-hoisted once (1 block/CU).
//   Phase 3: out = Apack @ Wout^T + bout -> [3968][7680] fp32
//            128x128 LDS-tiled MFMA GEMM w/ global_load_lds
//            + XOR-swizzled LDS chunks (bank-uniform ds_read_b128).

#define BT __hip_bfloat16

typedef short bf16x8 __attribute__((ext_vector_type(8)));
typedef float f32x4 __attribute__((ext_vector_type(4)));

__device__ __forceinline__ bf16x8 ld_frag(const BT* p) {
    return *reinterpret_cast<const bf16x8*>(p);
}
__device__ __forceinline__ f32x4 mfma16(bf16x8 a, bf16x8 b, f32x4 c) {
    return __builtin_amdgcn_mfma_f32_16x16x32_bf16(a, b, c, 0, 0, 0);
}
__device__ __forceinline__ float sigm(float x) { return 1.0f / (1.0f + __expf(-x)); }
// NaN-safe fast tanh: tanh(x) = sign(x) * (1-e)/(1+e), e = exp(-2|x|)
__device__ __forceinline__ float tanhfast(float x) {
    float e = __expf(-2.0f * fabsf(x));
    float r = (1.0f - e) / (1.0f + e);
    return copysignf(r, x);
}

// async 16B global -> LDS (wave-uniform LDS base + lane*16 hardware placement)
__device__ __forceinline__ void async16(const BT* g, BT* l) {
    __builtin_amdgcn_global_load_lds(
        (const __attribute__((address_space(1))) unsigned int*)g,
        (__attribute__((address_space(3))) unsigned int*)l,
        16, 0, 0);
}

union B4 { BT b[4]; unsigned long long u; };

// ---------------- Phase 0a: fp32 -> bf16 weight conversion ----------------
__global__ __launch_bounds__(256) void conv_kernel(
    const float* __restrict__ s0, const float* __restrict__ s1,
    const float* __restrict__ s2, const float* __restrict__ s3,
    const float* __restrict__ s4, BT* __restrict__ dbase)
{
    const int z = blockIdx.z;
    const float* src = (z == 0) ? s0 : (z == 1) ? s1 : (z == 2) ? s2 : (z == 3) ? s3 : s4;
    const int nel = (z == 4) ? 7864320 : 1048576;
    BT* dst = dbase + (long)z * 1048576;
    const int n4 = nel >> 2;
    for (int i = blockIdx.x * 256 + threadIdx.x; i < n4; i += gridDim.x * 256) {
        float4 v = reinterpret_cast<const float4*>(src)[i];
        B4 t;
        t.b[0] = __float2bfloat16(v.x); t.b[1] = __float2bfloat16(v.y);
        t.b[2] = __float2bfloat16(v.z); t.b[3] = __float2bfloat16(v.w);
        reinterpret_cast<unsigned long long*>(dst)[i] = t.u;
    }
}

// ---------------- Phase 0b: gather + convert embeddings ----------------
__global__ __launch_bounds__(256) void gather_kernel(
    const int* __restrict__ x, const float* __restrict__ emb, BT* __restrict__ Xemb)
{
    const int i = blockIdx.x * 256 + threadIdx.x;
    const int r = i >> 7;
    const int cq = i & 127;
    const long row = x[r];
    float4 v = reinterpret_cast<const float4*>(emb + row * 512)[cq];
    B4 t;
    t.b[0] = __float2bfloat16(v.x); t.b[1] = __float2bfloat16(v.y);
    t.b[2] = __float2bfloat16(v.z); t.b[3] = __float2bfloat16(v.w);
    reinterpret_cast<unsigned long long*>(Xemb + (long)r * 512)[cq] = t.u;
}

// ---------------- Phase 1: x-gates (also zero-inits the rec flags) --------
__global__ __launch_bounds__(256) void gx_kernel(
    const BT* __restrict__ Xemb,
    const BT* __restrict__ WihF, const BT* __restrict__ WihB,
    const float* __restrict__ bih_f, const float* __restrict__ bhh_f,
    const float* __restrict__ bih_b, const float* __restrict__ bhh_b,
    float* __restrict__ Gx, unsigned int* __restrict__ flags)
{
    const int dir = blockIdx.z;
    const BT* Wih = dir ? WihB : WihF;
    const float* bih = dir ? bih_b : bih_f;
    const float* bhh = dir ? bhh_b : bhh_f;
    float* G = Gx + (long)dir * 256 * 2048;

    const int tid = threadIdx.x;
    const int w = tid >> 6, lane = tid & 63;
    const int m = lane & 15, q = lane >> 4;
    const int r0 = blockIdx.x * 32;
    const int c0 = blockIdx.y * 128 + w * 32;

    if (tid == 0)
        flags[(blockIdx.z * 8 + blockIdx.x) * 16 + blockIdx.y] = 0;

    const BT* a0p = Xemb + (long)(r0 + m) * 512 + q * 8;
    const BT* a1p = Xemb + (long)(r0 + 16 + m) * 512 + q * 8;
    const BT* b0p = Wih + (long)(c0 + m) * 512 + q * 8;
    const BT* b1p = Wih + (long)(c0 + 16 + m) * 512 + q * 8;

    f32x4 acc[2][2] = {};
    for (int k0 = 0; k0 < 512; k0 += 32) {
        bf16x8 a0 = ld_frag(a0p + k0);
        bf16x8 a1 = ld_frag(a1p + k0);
        bf16x8 b0 = ld_frag(b0p + k0);
        bf16x8 b1 = ld_frag(b1p + k0);
        acc[0][0] = mfma16(a0, b0, acc[0][0]);
        acc[0][1] = mfma16(a0, b1, acc[0][1]);
        acc[1][0] = mfma16(a1, b0, acc[1][0]);
        acc[1][1] = mfma16(a1, b1, acc[1][1]);
    }
    #pragma unroll
    for (int rt = 0; rt < 2; ++rt)
        #pragma unroll
        for (int ct = 0; ct < 2; ++ct)
            #pragma unroll
            for (int reg = 0; reg < 4; ++reg) {
                int r = r0 + rt * 16 + q * 4 + reg;
                int c = c0 + ct * 16 + m;
                G[(long)r * 2048 + c] = acc[rt][ct][reg] + bih[c] + bhh[c];
            }
}

// ---------------- Phase 2: persistent recurrence, group barriers ----------
// grid (8,16,2) = 256 blocks (1 per CU), 256 threads (4 waves).
// Block (x,y,dir) owns chain rows x*32..+31 and gate-col slice y*32..+31
// (wave g handles gate g). Group = 16 blocks sharing (x,dir); the flag
// barrier syncs ONLY the group. Groups drift independently (group x idles
// until step 4x). Cooperative launch guarantees co-residency for the spin.
__global__ __launch_bounds__(256, 1) void rec_kernel(
    const BT* __restrict__ WhhF, const BT* __restrict__ WhhB,
    const float* __restrict__ Gx,
    BT* __restrict__ H0, BT* __restrict__ H1,
    float* __restrict__ C, float* __restrict__ S,
    BT* __restrict__ Apack, unsigned int* __restrict__ flags)
{
    const int dir = blockIdx.z;
    const int tid = threadIdx.x;
    const int w = tid >> 6, lane = tid & 63;
    const int m = lane & 15, q = lane >> 4;

    const BT* W = dir ? WhhB : WhhF;
    const float* G = Gx + (long)dir * 256 * 2048;
    BT* Ha = H0 + (long)dir * 256 * 512;
    BT* Hb = H1 + (long)dir * 256 * 512;
    float* Cd = C + (long)dir * 256 * 512;
    float* Sd = S + (long)dir * 256 * 512;

    const int r0 = blockIdx.x * 32;
    const int u0 = blockIdx.y * 32;
    unsigned int* flg = flags + (dir * 8 + blockIdx.x) * 16;
    const int myy = blockIdx.y;

    // hoist Whh fragments into registers (constant across all 32 steps)
    const BT* b0p = W + (long)(w * 512 + u0 + m) * 512 + q * 8;
    const BT* b1p = W + (long)(w * 512 + u0 + 16 + m) * 512 + q * 8;
    bf16x8 wb0[16], wb1[16];
    #pragma unroll
    for (int kk = 0; kk < 16; ++kk) {
        wb0[kk] = ld_frag(b0p + kk * 32);
        wb1[kk] = ld_frag(b1p + kk * 32);
    }

    __shared__ float gbuf[4][32][33];

    for (int s = 0; s < 32; ++s) {
        const BT* Hi = (s & 1) ? Hb : Ha;
        BT* Ho = (s & 1) ? Ha : Hb;
        if (r0 < 8 * (s + 1)) {   // block-uniform: any active chains in tile?
            const BT* a0p = Hi + (long)(r0 + m) * 512 + q * 8;
            const BT* a1p = Hi + (long)(r0 + 16 + m) * 512 + q * 8;
            f32x4 acc[2][2] = {};
            #pragma unroll
            for (int kk = 0; kk < 16; ++kk) {
                bf16x8 a0 = ld_frag(a0p + kk * 32);
                bf16x8 a1 = ld_frag(a1p + kk * 32);
                acc[0][0] = mfma16(a0, wb0[kk], acc[0][0]);
                acc[0][1] = mfma16(a0, wb1[kk], acc[0][1]);
                acc[1][0] = mfma16(a1, wb0[kk], acc[1][0]);
                acc[1][1] = mfma16(a1, wb1[kk], acc[1][1]);
            }
            #pragma unroll
            for (int rt = 0; rt < 2; ++rt)
                #pragma unroll
                for (int ct = 0; ct < 2; ++ct)
                    #pragma unroll
                    for (int reg = 0; reg < 4; ++reg)
                        gbuf[w][rt * 16 + q * 4 + reg][ct * 16 + m] = acc[rt][ct][reg];
            __syncthreads();

            const int pos = dir ? (31 - s) : s;
            for (int idx = tid; idx < 1024; idx += 256) {
                const int r = idx >> 5, ul = idx & 31;
                const int chain = r0 + r;
                const int d = chain >> 3;
                const int b = chain & 7;
                if (d > s) continue;
                const int u = u0 + ul;
                const float* gx = G + (long)(b * 32 + pos) * 2048 + u;
                const float gi = gbuf[0][r][ul] + gx[0];
                const float gf = gbuf[1][r][ul] + gx[512];
                const float gg = gbuf[2][r][ul] + gx[1024];
                const float go = gbuf[3][r][ul] + gx[1536];
                const long o = (long)chain * 512 + u;
                const float c_new = sigm(gf) * Cd[o] + sigm(gi) * tanhfast(gg);
                const float h = sigm(go) * tanhfast(c_new);
                Cd[o] = c_new;
                Ho[o] = __float2bfloat16(h);
                const float s_new = Sd[o] + h;
                Sd[o] = s_new;
                const int k = s - d;
                if (k >= 1) {
                    const int p_span = dir ? pos : d;
                    const int off = (k - 1) * 32 - ((k - 1) * k) / 2;
                    Apack[(long)(b * 496 + off + p_span) * 1024 + dir * 512 + u] =
                        __float2bfloat16(s_new * __builtin_amdgcn_rcpf((float)(k + 1)));
                }
            }
        }
        if (s == 31) break;   // no consumer inside kernel after last step

        // ---- group barrier: release H writes, wait for 16 partners ----
        __threadfence();          // agent-scope: publish this thread's writes
        __syncthreads();          // all block threads published before signal
        if (tid == 0)
            __hip_atomic_store(&flg[myy], (unsigned)(s + 1),
                               __ATOMIC_RELEASE, __HIP_MEMORY_SCOPE_AGENT);
        if (tid < 16) {
            while (__hip_atomic_load(&flg[tid], __ATOMIC_ACQUIRE,
                                     __HIP_MEMORY_SCOPE_AGENT) < (unsigned)(s + 1))
                __builtin_amdgcn_s_sleep(2);
        }
        __syncthreads();          // whole block waits on the spinners
        __threadfence();          // acquire: invalidate stale L1/L2 lines
    }
}

// ---------------- Phase 3: projection ----------------
// C[3968][7680] = Apack[3968][1024] @ Wout[7680][1024]^T + bout.
// grid (31, 60), block 256 = 4 waves (2x2 of 64x64); tile 128x128, BK=64.
// LDS tiles stored row-major [row][64] with XOR chunk swizzle:
//   LDS chunk slot s of row r holds global 8-elem chunk (s ^ (r&7)).
// Staging: lane i loads global chunk ((i&7)^(i>>3)) of row (L*8 + (i>>3)),
// which lands at LDS slot i*16B -> exactly the swizzled layout.
// Fragment reads then hit all 8 bank-quads uniformly (2 lanes/quad = free).
__global__ __launch_bounds__(256) void proj_kernel(
    const BT* __restrict__ Apack, const BT* __restrict__ Woutbf,
    const float* __restrict__ bout, float* __restrict__ out)
{
    __shared__ BT As[128 * 64];
    __shared__ BT Bs[128 * 64];

    const int tid = threadIdx.x;
    const int lane = tid & 63;
    const int wu = __builtin_amdgcn_readfirstlane(tid >> 6);
    const int m = lane & 15, q = lane >> 4;
    const int wr = wu >> 1, wc = wu & 1;
    const int r0 = blockIdx.x * 128;
    const int c0 = blockIdx.y * 128;

    const int srow = lane >> 3;             // 0..7 within 8-row staging group
    const int schunk = (lane & 7) ^ srow;   // swizzled global chunk index

    f32x4 acc[4][4] = {};

    for (int kc = 0; kc < 16; ++kc) {
        const int k0 = kc * 64;
        #pragma unroll
        for (int j = 0; j < 4; ++j) {
            const int L = wu * 4 + j;           // 0..15 staging group
            const int row = L * 8 + srow;       // 0..127 tile row
            async16(Apack + (long)(r0 + row) * 1024 + k0 + schunk * 8,
                    As + L * 512);
            async16(Woutbf + (long)(c0 + row) * 1024 + k0 + schunk * 8,
                    Bs + L * 512);
        }
        __syncthreads();
        #pragma unroll
        for (int ks = 0; ks < 2; ++ks) {
            const int slot = ((ks << 2) | q) ^ (m & 7);
            bf16x8 af[4], bf[4];
            #pragma unroll
            for (int t = 0; t < 4; ++t) {
                af[t] = ld_frag(As + (wr * 64 + t * 16 + m) * 64 + slot * 8);
                bf[t] = ld_frag(Bs + (wc * 64 + t * 16 + m) * 64 + slot * 8);
            }
            #pragma unroll
            for (int mt = 0; mt < 4; ++mt)
                #pragma unroll
                for (int nt = 0; nt < 4; ++nt)
                    acc[mt][nt] = mfma16(af[mt], bf[nt], acc[mt][nt]);
        }
        __syncthreads();
    }

    #pragma unroll
    for (int mt = 0; mt < 4; ++mt)
        #pragma unroll
        for (int nt = 0; nt < 4; ++nt)
            #pragma unroll
            for (int reg = 0; reg < 4; ++reg) {
                const int r = r0 + wr * 64 + mt * 16 + q * 4 + reg;
                const int c = c0 + wc * 64 + nt * 16 + m;
                out[(long)r * 7680 + c] = acc[mt][nt][reg] + bout[c];
            }
}

extern "C" void kernel_launch(void* const* d_in, const int* in_sizes, int n_in,
                              void* d_out, int out_size, void* d_ws, size_t ws_size,
                              hipStream_t stream) {
    const int*   x     = (const int*)d_in[0];
    const float* emb   = (const float*)d_in[2];
    const float* Wih_f = (const float*)d_in[3];
    const float* Whh_f = (const float*)d_in[4];
    const float* bih_f = (const float*)d_in[5];
    const float* bhh_f = (const float*)d_in[6];
    const float* Wih_b = (const float*)d_in[7];
    const float* Whh_b = (const float*)d_in[8];
    const float* bih_b = (const float*)d_in[9];
    const float* bhh_b = (const float*)d_in[10];
    const float* Wout  = (const float*)d_in[11];
    const float* bout  = (const float*)d_in[12];
    float* out = (float*)d_out;

    char* ws = (char*)d_ws;
    const long MB = 1 << 20;
    float* Gx    = (float*)(ws + 0);              // 4 MiB
    BT*    H0    = (BT*)(ws + 4 * MB);            // 512 KiB
    BT*    H1    = (BT*)(ws + 4 * MB + 512 * 1024);
    float* C     = (float*)(ws + 5 * MB);         // 1 MiB
    float* S     = (float*)(ws + 6 * MB);         // 1 MiB
    BT*    Apack = (BT*)(ws + 7 * MB);            // 7.75 MiB
    BT*    Xemb  = (BT*)(ws + 7 * MB + 7936 * 1024);  // 256 KiB
    BT*    Wbf   = (BT*)(ws + 15 * MB);           // 23 MiB -> ends at 38 MiB
    BT*    WihF  = Wbf;
    BT*    WihB  = Wbf + 1048576;
    BT*    WhhF  = Wbf + 2 * 1048576;
    BT*    WhhB  = Wbf + 3 * 1048576;
    BT*    Woutb = Wbf + 4 * 1048576;
    unsigned int* flags = (unsigned int*)(ws + 38 * MB);  // 1 KiB (16 grp x 16)

    hipMemsetAsync(ws + 4 * MB, 0, 3 * MB, stream);

    conv_kernel<<<dim3(512, 1, 5), 256, 0, stream>>>(
        Wih_f, Wih_b, Whh_f, Whh_b, Wout, Wbf);
    gather_kernel<<<128, 256, 0, stream>>>(x, emb, Xemb);

    gx_kernel<<<dim3(8, 16, 2), 256, 0, stream>>>(
        Xemb, WihF, WihB, bih_f, bhh_f, bih_b, bhh_b, Gx, flags);

    {
        void* args[] = {
            (void*)&WhhF, (void*)&WhhB, (void*)&Gx,
            (void*)&H0, (void*)&H1, (void*)&C, (void*)&S,
            (void*)&Apack, (void*)&flags
        };
        hipLaunchCooperativeKernel((const void*)rec_kernel, dim3(8, 16, 2),
                                   dim3(256, 1, 1), args, 0, stream);
    }

    proj_kernel<<<dim3(31, 60), 256, 0, stream>>>(Apack, Woutb, bout, out);
}

// Round 4
// 496.351 us; speedup vs baseline: 3.5545x; 3.5545x over previous
//
#include <hip/hip_runtime.h>
#include <hip/hip_bf16.h>

// SRNN text encoder, restructured (all device inputs/outputs are FP32):
//   Phase 0: convert Wih_f/Wih_b/Whh_f/Whh_b/Wout -> bf16 in ws; gather+convert
//            the 256 used embedding rows (Xemb).
//   Phase 1: Gx[dir][b*32+t][2048] = Xemb @ Wih^T + (bih+bhh)   (fp32) -- its
//            kernel-launch boundary doubles as the one full device sync.
//   Phase 2 (R7): ONE persistent cooperative kernel for all 32 recurrence
//            steps with a FENCELESS group barrier:
//              - R5 cg::grid.sync(): ~34 us/step.  R6 flag barrier with
//                __threadfence(): ~47 us/step (threadfence = buffer_wbl2 +
//                buffer_inv = full L2 flush per block per step).
//              - R7: publish ONLY the 2 KB H-slice via write-through
//                system-scope stores (sc0 sc1 -> LLC), s_waitcnt vmcnt(0),
//                then a system-scope flag store; partners spin on sc0 sc1
//                flag loads and read H with sc0 sc1 loads. No cache flushes.
//                Correct for ANY block->XCD placement (LLC is common point).
//            H staged once per block into XOR-swizzled LDS so the 4 waves
//            don't redundantly re-read the LLC. Whh frags register-hoisted.
//   Phase 3: out = Apack @ Wout^T + bout -> [3968][7680] fp32
//            128x128 LDS-tiled MFMA GEMM w/ global_load_lds
//            + XOR-swizzled LDS chunks (bank-uniform ds_read_b128).

#define BT __hip_bfloat16

typedef short bf16x8 __attribute__((ext_vector_type(8)));
typedef float f32x4 __attribute__((ext_vector_type(4)));

__device__ __forceinline__ bf16x8 ld_frag(const BT* p) {
    return *reinterpret_cast<const bf16x8*>(p);
}
__device__ __forceinline__ f32x4 mfma16(bf16x8 a, bf16x8 b, f32x4 c) {
    return __builtin_amdgcn_mfma_f32_16x16x32_bf16(a, b, c, 0, 0, 0);
}
__device__ __forceinline__ float sigm(float x) { return 1.0f / (1.0f + __expf(-x)); }
// NaN-safe fast tanh: tanh(x) = sign(x) * (1-e)/(1+e), e = exp(-2|x|)
__device__ __forceinline__ float tanhfast(float x) {
    float e = __expf(-2.0f * fabsf(x));
    float r = (1.0f - e) / (1.0f + e);
    return copysignf(r, x);
}

// ---- system-scope (LLC-coherent) accessors: bypass L1+L2, no fences ----
__device__ __forceinline__ bf16x8 ld_sys16(const BT* p) {
    bf16x8 r;
    asm volatile("global_load_dwordx4 %0, %1, off sc0 sc1"
                 : "=v"(r) : "v"(p) : "memory");
    return r;
}
__device__ __forceinline__ void st_sys_short(BT* p, BT v) {
    union { BT b; unsigned short u; } t; t.b = v;
    unsigned int d = t.u;
    asm volatile("global_store_short %0, %1, off sc0 sc1"
                 :: "v"(p), "v"(d) : "memory");
}
__device__ __forceinline__ void st_sys_u32(unsigned int* p, unsigned int v) {
    asm volatile("global_store_dword %0, %1, off sc0 sc1"
                 :: "v"(p), "v"(v) : "memory");
}
__device__ __forceinline__ unsigned int ld_sys_u32(const unsigned int* p) {
    unsigned int r;
    asm volatile("global_load_dword %0, %1, off sc0 sc1\n\t"
                 "s_waitcnt vmcnt(0)"
                 : "=v"(r) : "v"(p) : "memory");
    return r;
}

// async 16B global -> LDS (wave-uniform LDS base + lane*16 hardware placement)
__device__ __forceinline__ void async16(const BT* g, BT* l) {
    __builtin_amdgcn_global_load_lds(
        (const __attribute__((address_space(1))) unsigned int*)g,
        (__attribute__((address_space(3))) unsigned int*)l,
        16, 0, 0);
}

union B4 { BT b[4]; unsigned long long u; };

// ---------------- Phase 0a: fp32 -> bf16 weight conversion ----------------
__global__ __launch_bounds__(256) void conv_kernel(
    const float* __restrict__ s0, const float* __restrict__ s1,
    const float* __restrict__ s2, const float* __restrict__ s3,
    const float* __restrict__ s4, BT* __restrict__ dbase)
{
    const int z = blockIdx.z;
    const float* src = (z == 0) ? s0 : (z == 1) ? s1 : (z == 2) ? s2 : (z == 3) ? s3 : s4;
    const int nel = (z == 4) ? 7864320 : 1048576;
    BT* dst = dbase + (long)z * 1048576;
    const int n4 = nel >> 2;
    for (int i = blockIdx.x * 256 + threadIdx.x; i < n4; i += gridDim.x * 256) {
        float4 v = reinterpret_cast<const float4*>(src)[i];
        B4 t;
        t.b[0] = __float2bfloat16(v.x); t.b[1] = __float2bfloat16(v.y);
        t.b[2] = __float2bfloat16(v.z); t.b[3] = __float2bfloat16(v.w);
        reinterpret_cast<unsigned long long*>(dst)[i] = t.u;
    }
}

// ---------------- Phase 0b: gather + convert embeddings ----------------
__global__ __launch_bounds__(256) void gather_kernel(
    const int* __restrict__ x, const float* __restrict__ emb, BT* __restrict__ Xemb)
{
    const int i = blockIdx.x * 256 + threadIdx.x;
    const int r = i >> 7;
    const int cq = i & 127;
    const long row = x[r];
    float4 v = reinterpret_cast<const float4*>(emb + row * 512)[cq];
    B4 t;
    t.b[0] = __float2bfloat16(v.x); t.b[1] = __float2bfloat16(v.y);
    t.b[2] = __float2bfloat16(v.z); t.b[3] = __float2bfloat16(v.w);
    reinterpret_cast<unsigned long long*>(Xemb + (long)r * 512)[cq] = t.u;
}

// ---------------- Phase 1: x-gates (also inits rec flags at LLC) ----------
__global__ __launch_bounds__(256) void gx_kernel(
    const BT* __restrict__ Xemb,
    const BT* __restrict__ WihF, const BT* __restrict__ WihB,
    const float* __restrict__ bih_f, const float* __restrict__ bhh_f,
    const float* __restrict__ bih_b, const float* __restrict__ bhh_b,
    float* __restrict__ Gx, unsigned int* __restrict__ flags)
{
    const int dir = blockIdx.z;
    const BT* Wih = dir ? WihB : WihF;
    const float* bih = dir ? bih_b : bih_f;
    const float* bhh = dir ? bhh_b : bhh_f;
    float* G = Gx + (long)dir * 256 * 2048;

    const int tid = threadIdx.x;
    const int w = tid >> 6, lane = tid & 63;
    const int m = lane & 15, q = lane >> 4;
    const int r0 = blockIdx.x * 32;
    const int c0 = blockIdx.y * 128 + w * 32;

    if (tid == 0)   // write-through so rec's sc0sc1 polls can't see stale LLC
        st_sys_u32(&flags[(blockIdx.z * 8 + blockIdx.x) * 16 + blockIdx.y], 0u);

    const BT* a0p = Xemb + (long)(r0 + m) * 512 + q * 8;
    const BT* a1p = Xemb + (long)(r0 + 16 + m) * 512 + q * 8;
    const BT* b0p = Wih + (long)(c0 + m) * 512 + q * 8;
    const BT* b1p = Wih + (long)(c0 + 16 + m) * 512 + q * 8;

    f32x4 acc[2][2] = {};
    for (int k0 = 0; k0 < 512; k0 += 32) {
        bf16x8 a0 = ld_frag(a0p + k0);
        bf16x8 a1 = ld_frag(a1p + k0);
        bf16x8 b0 = ld_frag(b0p + k0);
        bf16x8 b1 = ld_frag(b1p + k0);
        acc[0][0] = mfma16(a0, b0, acc[0][0]);
        acc[0][1] = mfma16(a0, b1, acc[0][1]);
        acc[1][0] = mfma16(a1, b0, acc[1][0]);
        acc[1][1] = mfma16(a1, b1, acc[1][1]);
    }
    #pragma unroll
    for (int rt = 0; rt < 2; ++rt)
        #pragma unroll
        for (int ct = 0; ct < 2; ++ct)
            #pragma unroll
            for (int reg = 0; reg < 4; ++reg) {
                int r = r0 + rt * 16 + q * 4 + reg;
                int c = c0 + ct * 16 + m;
                G[(long)r * 2048 + c] = acc[rt][ct][reg] + bih[c] + bhh[c];
            }
}

// ---------------- Phase 2: persistent recurrence, fenceless barriers ------
// grid (8,16,2) = 256 blocks (1 per CU), 256 threads (4 waves).
// Block (x,y,dir) owns chain rows x*32..+31 and gate-col slice y*32..+31
// (wave g handles gate g). Group = 16 blocks sharing (x,dir). Per step:
//   stage Hi rows (32 KB) from LLC into XOR-swizzled LDS -> MFMA -> gates ->
//   write 2 KB H-slice write-through to LLC -> vmcnt(0) -> flag++ ->
//   spin on 16 partner flags. No threadfence, no L2 flushes.
__global__ __launch_bounds__(256, 1) void rec_kernel(
    const BT* __restrict__ WhhF, const BT* __restrict__ WhhB,
    const float* __restrict__ Gx,
    BT* __restrict__ H0, BT* __restrict__ H1,
    float* __restrict__ C, float* __restrict__ S,
    BT* __restrict__ Apack, unsigned int* __restrict__ flags)
{
    const int dir = blockIdx.z;
    const int tid = threadIdx.x;
    const int w = tid >> 6, lane = tid & 63;
    const int m = lane & 15, q = lane >> 4;

    const BT* W = dir ? WhhB : WhhF;
    const float* G = Gx + (long)dir * 256 * 2048;
    BT* Ha = H0 + (long)dir * 256 * 512;
    BT* Hb = H1 + (long)dir * 256 * 512;
    float* Cd = C + (long)dir * 256 * 512;
    float* Sd = S + (long)dir * 256 * 512;

    const int r0 = blockIdx.x * 32;
    const int u0 = blockIdx.y * 32;
    unsigned int* flg = flags + (dir * 8 + blockIdx.x) * 16;
    const int myy = blockIdx.y;

    // hoist Whh fragments (constant across all 32 steps; L2-hot reloads OK)
    const BT* b0p = W + (long)(w * 512 + u0 + m) * 512 + q * 8;
    const BT* b1p = W + (long)(w * 512 + u0 + 16 + m) * 512 + q * 8;
    bf16x8 wb0[16], wb1[16];
    #pragma unroll
    for (int kk = 0; kk < 16; ++kk) {
        wb0[kk] = ld_frag(b0p + kk * 32);
        wb1[kk] = ld_frag(b1p + kk * 32);
    }

    __shared__ float gbuf[4][32][33];
    __shared__ BT hbuf[32 * 512];           // 32 KB staged H tile (swizzled)

    const int srow = tid >> 3;              // 0..31 staging row
    const int sch0 = tid & 7;               // base chunk (of 64 8-elem chunks)
    const int xr = m & 7;                   // read-side XOR key

    for (int s = 0; s < 32; ++s) {
        const BT* Hi = (s & 1) ? Hb : Ha;
        BT* Ho = (s & 1) ? Ha : Hb;
        if (r0 < 8 * (s + 1)) {   // block-uniform: any active chains in tile?
            // ---- stage Hi rows r0..r0+31 (LLC-coherent) into swizzled LDS ----
            const BT* hsrc = Hi + (long)(r0 + srow) * 512;
            bf16x8 hv[8];
            #pragma unroll
            for (int rr = 0; rr < 8; ++rr)
                hv[rr] = ld_sys16(hsrc + (sch0 + rr * 8) * 8);
            asm volatile("s_waitcnt vmcnt(0)" ::: "memory");
            __builtin_amdgcn_sched_barrier(0);
            #pragma unroll
            for (int rr = 0; rr < 8; ++rr) {
                const int ch = sch0 + rr * 8;
                *reinterpret_cast<bf16x8*>(
                    hbuf + srow * 512 + (ch ^ (srow & 7)) * 8) = hv[rr];
            }
            __syncthreads();

            // ---- gate GEMM: gbuf = Hi @ Whh_slice^T ----
            f32x4 acc[2][2] = {};
            #pragma unroll
            for (int kk = 0; kk < 16; ++kk) {
                const int sl = (((kk << 2) | q) ^ xr) * 8;
                bf16x8 a0 = *reinterpret_cast<const bf16x8*>(hbuf + m * 512 + sl);
                bf16x8 a1 = *reinterpret_cast<const bf16x8*>(hbuf + (16 + m) * 512 + sl);
                acc[0][0] = mfma16(a0, wb0[kk], acc[0][0]);
                acc[0][1] = mfma16(a0, wb1[kk], acc[0][1]);
                acc[1][0] = mfma16(a1, wb0[kk], acc[1][0]);
                acc[1][1] = mfma16(a1, wb1[kk], acc[1][1]);
            }
            #pragma unroll
            for (int rt = 0; rt < 2; ++rt)
                #pragma unroll
                for (int ct = 0; ct < 2; ++ct)
                    #pragma unroll
                    for (int reg = 0; reg < 4; ++reg)
                        gbuf[w][rt * 16 + q * 4 + reg][ct * 16 + m] = acc[rt][ct][reg];
            __syncthreads();

            // ---- elementwise LSTM cell + prefix-sum + span-mean pack ----
            const int pos = dir ? (31 - s) : s;
            for (int idx = tid; idx < 1024; idx += 256) {
                const int r = idx >> 5, ul = idx & 31;
                const int chain = r0 + r;
                const int d = chain >> 3;
                const int b = chain & 7;
                if (d > s) continue;
                const int u = u0 + ul;
                const float* gx = G + (long)(b * 32 + pos) * 2048 + u;
                const float gi = gbuf[0][r][ul] + gx[0];
                const float gf = gbuf[1][r][ul] + gx[512];
                const float gg = gbuf[2][r][ul] + gx[1024];
                const float go = gbuf[3][r][ul] + gx[1536];
                const long o = (long)chain * 512 + u;
                const float c_new = sigm(gf) * Cd[o] + sigm(gi) * tanhfast(gg);
                const float h = sigm(go) * tanhfast(c_new);
                Cd[o] = c_new;
                st_sys_short(Ho + o, __float2bfloat16(h));   // write-through
                const float s_new = Sd[o] + h;
                Sd[o] = s_new;
                const int k = s - d;
                if (k >= 1) {
                    const int p_span = dir ? pos : d;
                    const int off = (k - 1) * 32 - ((k - 1) * k) / 2;
                    Apack[(long)(b * 496 + off + p_span) * 1024 + dir * 512 + u] =
                        __float2bfloat16(s_new * __builtin_amdgcn_rcpf((float)(k + 1)));
                }
            }
        }
        if (s == 31) break;   // no in-kernel consumer after the last step

        // ---- fenceless group barrier (H already at LLC via sc0 sc1) ----
        asm volatile("s_waitcnt vmcnt(0)" ::: "memory");  // per-wave drain
        __syncthreads();                                  // all waves drained
        if (tid == 0)
            st_sys_u32(&flg[myy], (unsigned)(s + 1));
        if (tid < 16) {
            const unsigned int tgt = (unsigned)(s + 1);
            while (ld_sys_u32(&flg[tid]) < tgt)
                __builtin_amdgcn_s_sleep(1);
        }
        __syncthreads();
        asm volatile("" ::: "memory");   // no reordering across the barrier
    }
}

// ---------------- Phase 3: projection ----------------
// C[3968][7680] = Apack[3968][1024] @ Wout[7680][1024]^T + bout.
// grid (31, 60), block 256 = 4 waves (2x2 of 64x64); tile 128x128, BK=64.
// LDS tiles stored row-major [row][64] with XOR chunk swizzle.
__global__ __launch_bounds__(256) void proj_kernel(
    const BT* __restrict__ Apack, const BT* __restrict__ Woutbf,
    const float* __restrict__ bout, float* __restrict__ out)
{
    __shared__ BT As[128 * 64];
    __shared__ BT Bs[128 * 64];

    const int tid = threadIdx.x;
    const int lane = tid & 63;
    const int wu = __builtin_amdgcn_readfirstlane(tid >> 6);
    const int m = lane & 15, q = lane >> 4;
    const int wr = wu >> 1, wc = wu & 1;
    const int r0 = blockIdx.x * 128;
    const int c0 = blockIdx.y * 128;

    const int srow = lane >> 3;             // 0..7 within 8-row staging group
    const int schunk = (lane & 7) ^ srow;   // swizzled global chunk index

    f32x4 acc[4][4] = {};

    for (int kc = 0; kc < 16; ++kc) {
        const int k0 = kc * 64;
        #pragma unroll
        for (int j = 0; j < 4; ++j) {
            const int L = wu * 4 + j;           // 0..15 staging group
            const int row = L * 8 + srow;       // 0..127 tile row
            async16(Apack + (long)(r0 + row) * 1024 + k0 + schunk * 8,
                    As + L * 512);
            async16(Woutbf + (long)(c0 + row) * 1024 + k0 + schunk * 8,
                    Bs + L * 512);
        }
        __syncthreads();
        #pragma unroll
        for (int ks = 0; ks < 2; ++ks) {
            const int slot = ((ks << 2) | q) ^ (m & 7);
            bf16x8 af[4], bf[4];
            #pragma unroll
            for (int t = 0; t < 4; ++t) {
                af[t] = ld_frag(As + (wr * 64 + t * 16 + m) * 64 + slot * 8);
                bf[t] = ld_frag(Bs + (wc * 64 + t * 16 + m) * 64 + slot * 8);
            }
            #pragma unroll
            for (int mt = 0; mt < 4; ++mt)
                #pragma unroll
                for (int nt = 0; nt < 4; ++nt)
                    acc[mt][nt] = mfma16(af[mt], bf[nt], acc[mt][nt]);
        }
        __syncthreads();
    }

    #pragma unroll
    for (int mt = 0; mt < 4; ++mt)
        #pragma unroll
        for (int nt = 0; nt < 4; ++nt)
            #pragma unroll
            for (int reg = 0; reg < 4; ++reg) {
                const int r = r0 + wr * 64 + mt * 16 + q * 4 + reg;
                const int c = c0 + wc * 64 + nt * 16 + m;
                out[(long)r * 7680 + c] = acc[mt][nt][reg] + bout[c];
            }
}

extern "C" void kernel_launch(void* const* d_in, const int* in_sizes, int n_in,
                              void* d_out, int out_size, void* d_ws, size_t ws_size,
                              hipStream_t stream) {
    const int*   x     = (const int*)d_in[0];
    const float* emb   = (const float*)d_in[2];
    const float* Wih_f = (const float*)d_in[3];
    const float* Whh_f = (const float*)d_in[4];
    const float* bih_f = (const float*)d_in[5];
    const float* bhh_f = (const float*)d_in[6];
    const float* Wih_b = (const float*)d_in[7];
    const float* Whh_b = (const float*)d_in[8];
    const float* bih_b = (const float*)d_in[9];
    const float* bhh_b = (const float*)d_in[10];
    const float* Wout  = (const float*)d_in[11];
    const float* bout  = (const float*)d_in[12];
    float* out = (float*)d_out;

    char* ws = (char*)d_ws;
    const long MB = 1 << 20;
    float* Gx    = (float*)(ws + 0);              // 4 MiB
    BT*    H0    = (BT*)(ws + 4 * MB);            // 512 KiB
    BT*    H1    = (BT*)(ws + 4 * MB + 512 * 1024);
    float* C     = (float*)(ws + 5 * MB);         // 1 MiB
    float* S     = (float*)(ws + 6 * MB);         // 1 MiB
    BT*    Apack = (BT*)(ws + 7 * MB);            // 7.75 MiB
    BT*    Xemb  = (BT*)(ws + 7 * MB + 7936 * 1024);  // 256 KiB
    BT*    Wbf   = (BT*)(ws + 15 * MB);           // 23 MiB -> ends at 38 MiB
    BT*    WihF  = Wbf;
    BT*    WihB  = Wbf + 1048576;
    BT*    WhhF  = Wbf + 2 * 1048576;
    BT*    WhhB  = Wbf + 3 * 1048576;
    BT*    Woutb = Wbf + 4 * 1048576;
    unsigned int* flags = (unsigned int*)(ws + 38 * MB);  // 1 KiB (16 grp x 16)

    hipMemsetAsync(ws + 4 * MB, 0, 3 * MB, stream);

    conv_kernel<<<dim3(512, 1, 5), 256, 0, stream>>>(
        Wih_f, Wih_b, Whh_f, Whh_b, Wout, Wbf);
    gather_kernel<<<128, 256, 0, stream>>>(x, emb, Xemb);

    gx_kernel<<<dim3(8, 16, 2), 256, 0, stream>>>(
        Xemb, WihF, WihB, bih_f, bhh_f, bih_b, bhh_b, Gx, flags);

    {
        void* args[] = {
            (void*)&WhhF, (void*)&WhhB, (void*)&Gx,
            (void*)&H0, (void*)&H1, (void*)&C, (void*)&S,
            (void*)&Apack, (void*)&flags
        };
        hipLaunchCooperativeKernel((const void*)rec_kernel, dim3(8, 16, 2),
                                   dim3(256, 1, 1), args, 0, stream);
    }

    proj_kernel<<<dim3(31, 60), 256, 0, stream>>>(Apack, Woutb, bout, out);
}

// Round 5
// 456.140 us; speedup vs baseline: 3.8678x; 1.0882x over previous
//
#include <hip/hip_runtime.h>
#include <hip/hip_bf16.h>

// SRNN text encoder, restructured (all device inputs/outputs are FP32):
//   Phase 0: convert Wih_f/Wih_b/Whh_f/Whh_b/Wout -> bf16 in ws; gather+convert
//            the 256 used embedding rows (Xemb).
//   Phase 1: Gx[dir][b*32+t][2048] = Xemb @ Wih^T + (bih+bhh)   (fp32)
//   Phase 2 (R8): ONE persistent kernel for all 32 recurrence steps with the
//            fenceless LLC group barrier (R7: 5.7 us/step, rec=182 us).
//            R8 changes:
//              - NORMAL launch instead of hipLaunchCooperativeKernel: the
//                coop path measured ~150-220 us of driver overhead per
//                invocation (total-minus-rec was 246-314 us across R5-R7 vs
//                ~97 us with plain launches). Co-residency is guaranteed
//                without coop: 1024 waves vs 8192 slots; even 2 blocks/CU
//                fit (2x49.6KB LDS, 8x116 VGPR) -> spin cannot deadlock.
//              - Early signal: store H-slice + flag BEFORE the S/Apack
//                bookkeeping, so partners' poll latency hides it.
//   Phase 3: out = Apack @ Wout^T + bout -> [3968][7680] fp32
//            128x128 LDS-tiled MFMA GEMM w/ global_load_lds
//            + XOR-swizzled LDS chunks (bank-uniform ds_read_b128).

#define BT __hip_bfloat16

typedef short bf16x8 __attribute__((ext_vector_type(8)));
typedef float f32x4 __attribute__((ext_vector_type(4)));

__device__ __forceinline__ bf16x8 ld_frag(const BT* p) {
    return *reinterpret_cast<const bf16x8*>(p);
}
__device__ __forceinline__ f32x4 mfma16(bf16x8 a, bf16x8 b, f32x4 c) {
    return __builtin_amdgcn_mfma_f32_16x16x32_bf16(a, b, c, 0, 0, 0);
}
__device__ __forceinline__ float sigm(float x) { return 1.0f / (1.0f + __expf(-x)); }
// NaN-safe fast tanh: tanh(x) = sign(x) * (1-e)/(1+e), e = exp(-2|x|)
__device__ __forceinline__ float tanhfast(float x) {
    float e = __expf(-2.0f * fabsf(x));
    float r = (1.0f - e) / (1.0f + e);
    return copysignf(r, x);
}

// ---- system-scope (LLC-coherent) accessors: bypass L1+L2, no fences ----
__device__ __forceinline__ bf16x8 ld_sys16(const BT* p) {
    bf16x8 r;
    asm volatile("global_load_dwordx4 %0, %1, off sc0 sc1"
                 : "=v"(r) : "v"(p) : "memory");
    return r;
}
__device__ __forceinline__ void st_sys_short(BT* p, BT v) {
    union { BT b; unsigned short u; } t; t.b = v;
    unsigned int d = t.u;
    asm volatile("global_store_short %0, %1, off sc0 sc1"
                 :: "v"(p), "v"(d) : "memory");
}
__device__ __forceinline__ void st_sys_u32(unsigned int* p, unsigned int v) {
    asm volatile("global_store_dword %0, %1, off sc0 sc1"
                 :: "v"(p), "v"(v) : "memory");
}
__device__ __forceinline__ unsigned int ld_sys_u32(const unsigned int* p) {
    unsigned int r;
    asm volatile("global_load_dword %0, %1, off sc0 sc1\n\t"
                 "s_waitcnt vmcnt(0)"
                 : "=v"(r) : "v"(p) : "memory");
    return r;
}

// async 16B global -> LDS (wave-uniform LDS base + lane*16 hardware placement)
__device__ __forceinline__ void async16(const BT* g, BT* l) {
    __builtin_amdgcn_global_load_lds(
        (const __attribute__((address_space(1))) unsigned int*)g,
        (__attribute__((address_space(3))) unsigned int*)l,
        16, 0, 0);
}

union B4 { BT b[4]; unsigned long long u; };

// ---------------- Phase 0a: fp32 -> bf16 weight conversion ----------------
__global__ __launch_bounds__(256) void conv_kernel(
    const float* __restrict__ s0, const float* __restrict__ s1,
    const float* __restrict__ s2, const float* __restrict__ s3,
    const float* __restrict__ s4, BT* __restrict__ dbase)
{
    const int z = blockIdx.z;
    const float* src = (z == 0) ? s0 : (z == 1) ? s1 : (z == 2) ? s2 : (z == 3) ? s3 : s4;
    const int nel = (z == 4) ? 7864320 : 1048576;
    BT* dst = dbase + (long)z * 1048576;
    const int n4 = nel >> 2;
    for (int i = blockIdx.x * 256 + threadIdx.x; i < n4; i += gridDim.x * 256) {
        float4 v = reinterpret_cast<const float4*>(src)[i];
        B4 t;
        t.b[0] = __float2bfloat16(v.x); t.b[1] = __float2bfloat16(v.y);
        t.b[2] = __float2bfloat16(v.z); t.b[3] = __float2bfloat16(v.w);
        reinterpret_cast<unsigned long long*>(dst)[i] = t.u;
    }
}

// ---------------- Phase 0b: gather + convert embeddings ----------------
__global__ __launch_bounds__(256) void gather_kernel(
    const int* __restrict__ x, const float* __restrict__ emb, BT* __restrict__ Xemb)
{
    const int i = blockIdx.x * 256 + threadIdx.x;
    const int r = i >> 7;
    const int cq = i & 127;
    const long row = x[r];
    float4 v = reinterpret_cast<const float4*>(emb + row * 512)[cq];
    B4 t;
    t.b[0] = __float2bfloat16(v.x); t.b[1] = __float2bfloat16(v.y);
    t.b[2] = __float2bfloat16(v.z); t.b[3] = __float2bfloat16(v.w);
    reinterpret_cast<unsigned long long*>(Xemb + (long)r * 512)[cq] = t.u;
}

// ---------------- Phase 1: x-gates (also inits rec flags at LLC) ----------
__global__ __launch_bounds__(256) void gx_kernel(
    const BT* __restrict__ Xemb,
    const BT* __restrict__ WihF, const BT* __restrict__ WihB,
    const float* __restrict__ bih_f, const float* __restrict__ bhh_f,
    const float* __restrict__ bih_b, const float* __restrict__ bhh_b,
    float* __restrict__ Gx, unsigned int* __restrict__ flags)
{
    const int dir = blockIdx.z;
    const BT* Wih = dir ? WihB : WihF;
    const float* bih = dir ? bih_b : bih_f;
    const float* bhh = dir ? bhh_b : bhh_f;
    float* G = Gx + (long)dir * 256 * 2048;

    const int tid = threadIdx.x;
    const int w = tid >> 6, lane = tid & 63;
    const int m = lane & 15, q = lane >> 4;
    const int r0 = blockIdx.x * 32;
    const int c0 = blockIdx.y * 128 + w * 32;

    if (tid == 0)   // write-through so rec's sc0sc1 polls can't see stale LLC
        st_sys_u32(&flags[(blockIdx.z * 8 + blockIdx.x) * 16 + blockIdx.y], 0u);

    const BT* a0p = Xemb + (long)(r0 + m) * 512 + q * 8;
    const BT* a1p = Xemb + (long)(r0 + 16 + m) * 512 + q * 8;
    const BT* b0p = Wih + (long)(c0 + m) * 512 + q * 8;
    const BT* b1p = Wih + (long)(c0 + 16 + m) * 512 + q * 8;

    f32x4 acc[2][2] = {};
    for (int k0 = 0; k0 < 512; k0 += 32) {
        bf16x8 a0 = ld_frag(a0p + k0);
        bf16x8 a1 = ld_frag(a1p + k0);
        bf16x8 b0 = ld_frag(b0p + k0);
        bf16x8 b1 = ld_frag(b1p + k0);
        acc[0][0] = mfma16(a0, b0, acc[0][0]);
        acc[0][1] = mfma16(a0, b1, acc[0][1]);
        acc[1][0] = mfma16(a1, b0, acc[1][0]);
        acc[1][1] = mfma16(a1, b1, acc[1][1]);
    }
    #pragma unroll
    for (int rt = 0; rt < 2; ++rt)
        #pragma unroll
        for (int ct = 0; ct < 2; ++ct)
            #pragma unroll
            for (int reg = 0; reg < 4; ++reg) {
                int r = r0 + rt * 16 + q * 4 + reg;
                int c = c0 + ct * 16 + m;
                G[(long)r * 2048 + c] = acc[rt][ct][reg] + bih[c] + bhh[c];
            }
}

// ---------------- Phase 2: persistent recurrence, fenceless barriers ------
// grid (8,16,2) = 256 blocks (1 per CU), 256 threads (4 waves).
// Block (x,y,dir) owns chain rows x*32..+31 and gate-col slice y*32..+31
// (wave g handles gate g). Group = 16 blocks sharing (x,dir). Per step:
//   stage Hi rows (32 KB, LLC) into XOR-swizzled LDS -> MFMA -> gates ->
//   cell update -> write 2 KB H-slice write-through -> vmcnt(0) -> flag++ ->
//   [S/Apack bookkeeping overlaps partners' latency] -> spin on 16 flags.
__global__ __launch_bounds__(256, 1) void rec_kernel(
    const BT* __restrict__ WhhF, const BT* __restrict__ WhhB,
    const float* __restrict__ Gx,
    BT* __restrict__ H0, BT* __restrict__ H1,
    float* __restrict__ C, float* __restrict__ S,
    BT* __restrict__ Apack, unsigned int* __restrict__ flags)
{
    const int dir = blockIdx.z;
    const int tid = threadIdx.x;
    const int w = tid >> 6, lane = tid & 63;
    const int m = lane & 15, q = lane >> 4;

    const BT* W = dir ? WhhB : WhhF;
    const float* G = Gx + (long)dir * 256 * 2048;
    BT* Ha = H0 + (long)dir * 256 * 512;
    BT* Hb = H1 + (long)dir * 256 * 512;
    float* Cd = C + (long)dir * 256 * 512;
    float* Sd = S + (long)dir * 256 * 512;

    const int r0 = blockIdx.x * 32;
    const int u0 = blockIdx.y * 32;
    unsigned int* flg = flags + (dir * 8 + blockIdx.x) * 16;
    const int myy = blockIdx.y;

    // hoist Whh fragments (constant across all 32 steps)
    const BT* b0p = W + (long)(w * 512 + u0 + m) * 512 + q * 8;
    const BT* b1p = W + (long)(w * 512 + u0 + 16 + m) * 512 + q * 8;
    bf16x8 wb0[16], wb1[16];
    #pragma unroll
    for (int kk = 0; kk < 16; ++kk) {
        wb0[kk] = ld_frag(b0p + kk * 32);
        wb1[kk] = ld_frag(b1p + kk * 32);
    }

    __shared__ float gbuf[4][32][33];
    __shared__ BT hbuf[32 * 512];           // 32 KB staged H tile (swizzled)

    const int srow = tid >> 3;              // 0..31 staging row
    const int sch0 = tid & 7;               // base chunk (of 64 8-elem chunks)
    const int xr = m & 7;                   // read-side XOR key

    for (int s = 0; s < 32; ++s) {
        const BT* Hi = (s & 1) ? Hb : Ha;
        BT* Ho = (s & 1) ? Ha : Hb;
        const bool active = (r0 < 8 * (s + 1));
        const int pos = dir ? (31 - s) : s;
        float hreg[4];

        if (active) {
            // ---- stage Hi rows r0..r0+31 (LLC-coherent) into swizzled LDS ----
            const BT* hsrc = Hi + (long)(r0 + srow) * 512;
            bf16x8 hv[8];
            #pragma unroll
            for (int rr = 0; rr < 8; ++rr)
                hv[rr] = ld_sys16(hsrc + (sch0 + rr * 8) * 8);
            asm volatile("s_waitcnt vmcnt(0)" ::: "memory");
            __builtin_amdgcn_sched_barrier(0);
            #pragma unroll
            for (int rr = 0; rr < 8; ++rr) {
                const int ch = sch0 + rr * 8;
                *reinterpret_cast<bf16x8*>(
                    hbuf + srow * 512 + (ch ^ (srow & 7)) * 8) = hv[rr];
            }
            __syncthreads();

            // ---- gate GEMM: gbuf = Hi @ Whh_slice^T ----
            f32x4 acc[2][2] = {};
            #pragma unroll
            for (int kk = 0; kk < 16; ++kk) {
                const int sl = (((kk << 2) | q) ^ xr) * 8;
                bf16x8 a0 = *reinterpret_cast<const bf16x8*>(hbuf + m * 512 + sl);
                bf16x8 a1 = *reinterpret_cast<const bf16x8*>(hbuf + (16 + m) * 512 + sl);
                acc[0][0] = mfma16(a0, wb0[kk], acc[0][0]);
                acc[0][1] = mfma16(a0, wb1[kk], acc[0][1]);
                acc[1][0] = mfma16(a1, wb0[kk], acc[1][0]);
                acc[1][1] = mfma16(a1, wb1[kk], acc[1][1]);
            }
            #pragma unroll
            for (int rt = 0; rt < 2; ++rt)
                #pragma unroll
                for (int ct = 0; ct < 2; ++ct)
                    #pragma unroll
                    for (int reg = 0; reg < 4; ++reg)
                        gbuf[w][rt * 16 + q * 4 + reg][ct * 16 + m] = acc[rt][ct][reg];
            __syncthreads();

            // ---- pass 1: cell update, publish h (critical for partners) ----
            #pragma unroll
            for (int j = 0; j < 4; ++j) {
                const int idx = tid + j * 256;
                const int r = idx >> 5, ul = idx & 31;
                const int chain = r0 + r;
                const int d = chain >> 3;
                const int b = chain & 7;
                if (d > s) continue;
                const int u = u0 + ul;
                const float* gx = G + (long)(b * 32 + pos) * 2048 + u;
                const float gi = gbuf[0][r][ul] + gx[0];
                const float gf = gbuf[1][r][ul] + gx[512];
                const float gg = gbuf[2][r][ul] + gx[1024];
                const float go = gbuf[3][r][ul] + gx[1536];
                const long o = (long)chain * 512 + u;
                const float c_new = sigm(gf) * Cd[o] + sigm(gi) * tanhfast(gg);
                const float h = sigm(go) * tanhfast(c_new);
                Cd[o] = c_new;
                st_sys_short(Ho + o, __float2bfloat16(h));   // write-through
                hreg[j] = h;
            }
        }

        // ---- signal as early as possible (H already at LLC) ----
        if (s < 31) {
            asm volatile("s_waitcnt vmcnt(0)" ::: "memory");  // drain H stores
            __syncthreads();                                  // all waves done
            if (tid == 0)
                st_sys_u32(&flg[myy], (unsigned)(s + 1));
        }

        // ---- pass 2: prefix-sum + span-mean pack (hidden by partner latency)
        if (active) {
            #pragma unroll
            for (int j = 0; j < 4; ++j) {
                const int idx = tid + j * 256;
                const int r = idx >> 5, ul = idx & 31;
                const int chain = r0 + r;
                const int d = chain >> 3;
                const int b = chain & 7;
                if (d > s) continue;
                const int u = u0 + ul;
                const long o = (long)chain * 512 + u;
                const float s_new = Sd[o] + hreg[j];
                Sd[o] = s_new;
                const int k = s - d;
                if (k >= 1) {
                    const int p_span = dir ? pos : d;
                    const int off = (k - 1) * 32 - ((k - 1) * k) / 2;
                    Apack[(long)(b * 496 + off + p_span) * 1024 + dir * 512 + u] =
                        __float2bfloat16(s_new * __builtin_amdgcn_rcpf((float)(k + 1)));
                }
            }
        }

        // ---- wait for 16 partners ----
        if (s < 31) {
            if (tid < 16) {
                const unsigned int tgt = (unsigned)(s + 1);
                while (ld_sys_u32(&flg[tid]) < tgt)
                    __builtin_amdgcn_s_sleep(1);
            }
            __syncthreads();
            asm volatile("" ::: "memory");   // no reordering across barrier
        }
    }
}

// ---------------- Phase 3: projection ----------------
// C[3968][7680] = Apack[3968][1024] @ Wout[7680][1024]^T + bout.
// grid (31, 60), block 256 = 4 waves (2x2 of 64x64); tile 128x128, BK=64.
// LDS tiles stored row-major [row][64] with XOR chunk swizzle.
__global__ __launch_bounds__(256) void proj_kernel(
    const BT* __restrict__ Apack, const BT* __restrict__ Woutbf,
    const float* __restrict__ bout, float* __restrict__ out)
{
    __shared__ BT As[128 * 64];
    __shared__ BT Bs[128 * 64];

    const int tid = threadIdx.x;
    const int lane = tid & 63;
    const int wu = __builtin_amdgcn_readfirstlane(tid >> 6);
    const int m = lane & 15, q = lane >> 4;
    const int wr = wu >> 1, wc = wu & 1;
    const int r0 = blockIdx.x * 128;
    const int c0 = blockIdx.y * 128;

    const int srow = lane >> 3;             // 0..7 within 8-row staging group
    const int schunk = (lane & 7) ^ srow;   // swizzled global chunk index

    f32x4 acc[4][4] = {};

    for (int kc = 0; kc < 16; ++kc) {
        const int k0 = kc * 64;
        #pragma unroll
        for (int j = 0; j < 4; ++j) {
            const int L = wu * 4 + j;           // 0..15 staging group
            const int row = L * 8 + srow;       // 0..127 tile row
            async16(Apack + (long)(r0 + row) * 1024 + k0 + schunk * 8,
                    As + L * 512);
            async16(Woutbf + (long)(c0 + row) * 1024 + k0 + schunk * 8,
                    Bs + L * 512);
        }
        __syncthreads();
        #pragma unroll
        for (int ks = 0; ks < 2; ++ks) {
            const int slot = ((ks << 2) | q) ^ (m & 7);
            bf16x8 af[4], bf[4];
            #pragma unroll
            for (int t = 0; t < 4; ++t) {
                af[t] = ld_frag(As + (wr * 64 + t * 16 + m) * 64 + slot * 8);
                bf[t] = ld_frag(Bs + (wc * 64 + t * 16 + m) * 64 + slot * 8);
            }
            #pragma unroll
            for (int mt = 0; mt < 4; ++mt)
                #pragma unroll
                for (int nt = 0; nt < 4; ++nt)
                    acc[mt][nt] = mfma16(af[mt], bf[nt], acc[mt][nt]);
        }
        __syncthreads();
    }

    #pragma unroll
    for (int mt = 0; mt < 4; ++mt)
        #pragma unroll
        for (int nt = 0; nt < 4; ++nt)
            #pragma unroll
            for (int reg = 0; reg < 4; ++reg) {
                const int r = r0 + wr * 64 + mt * 16 + q * 4 + reg;
                const int c = c0 + wc * 64 + nt * 16 + m;
                out[(long)r * 7680 + c] = acc[mt][nt][reg] + bout[c];
            }
}

extern "C" void kernel_launch(void* const* d_in, const int* in_sizes, int n_in,
                              void* d_out, int out_size, void* d_ws, size_t ws_size,
                              hipStream_t stream) {
    const int*   x     = (const int*)d_in[0];
    const float* emb   = (const float*)d_in[2];
    const float* Wih_f = (const float*)d_in[3];
    const float* Whh_f = (const float*)d_in[4];
    const float* bih_f = (const float*)d_in[5];
    const float* bhh_f = (const float*)d_in[6];
    const float* Wih_b = (const float*)d_in[7];
    const float* Whh_b = (const float*)d_in[8];
    const float* bih_b = (const float*)d_in[9];
    const float* bhh_b = (const float*)d_in[10];
    const float* Wout  = (const float*)d_in[11];
    const float* bout  = (const float*)d_in[12];
    float* out = (float*)d_out;

    char* ws = (char*)d_ws;
    const long MB = 1 << 20;
    float* Gx    = (float*)(ws + 0);              // 4 MiB
    BT*    H0    = (BT*)(ws + 4 * MB);            // 512 KiB
    BT*    H1    = (BT*)(ws + 4 * MB + 512 * 1024);
    float* C     = (float*)(ws + 5 * MB);         // 1 MiB
    float* S     = (float*)(ws + 6 * MB);         // 1 MiB
    BT*    Apack = (BT*)(ws + 7 * MB);            // 7.75 MiB
    BT*    Xemb  = (BT*)(ws + 7 * MB + 7936 * 1024);  // 256 KiB
    BT*    Wbf   = (BT*)(ws + 15 * MB);           // 23 MiB -> ends at 38 MiB
    BT*    WihF  = Wbf;
    BT*    WihB  = Wbf + 1048576;
    BT*    WhhF  = Wbf + 2 * 1048576;
    BT*    WhhB  = Wbf + 3 * 1048576;
    BT*    Woutb = Wbf + 4 * 1048576;
    unsigned int* flags = (unsigned int*)(ws + 38 * MB);  // 1 KiB (16 grp x 16)

    hipMemsetAsync(ws + 4 * MB, 0, 3 * MB, stream);

    conv_kernel<<<dim3(512, 1, 5), 256, 0, stream>>>(
        Wih_f, Wih_b, Whh_f, Whh_b, Wout, Wbf);
    gather_kernel<<<128, 256, 0, stream>>>(x, emb, Xemb);

    gx_kernel<<<dim3(8, 16, 2), 256, 0, stream>>>(
        Xemb, WihF, WihB, bih_f, bhh_f, bih_b, bhh_b, Gx, flags);

    // Plain launch: 256 blocks x 4 waves = 1024 waves << 8192 slots; all
    // blocks resident regardless of placement -> spin barrier is safe.
    rec_kernel<<<dim3(8, 16, 2), 256, 0, stream>>>(
        WhhF, WhhB, Gx, H0, H1, C, S, Apack, flags);

    proj_kernel<<<dim3(31, 60), 256, 0, stream>>>(Apack, Woutb, bout, out);
}

// Round 6
// 411.461 us; speedup vs baseline: 4.2878x; 1.1086x over previous
//
#include <hip/hip_runtime.h>
#include <hip/hip_bf16.h>

// SRNN text encoder, restructured (all device inputs/outputs are FP32):
//   Phase 0 (prep): convert Wih_f/Wih_b/Whh_f/Whh_b/Wout -> bf16 in ws (z=0..4)
//            and gather+convert the 256 used embedding rows (z=5).
//   Phase 1: Gx[dir][b*32+t][2048] = Xemb @ Wih^T + (bih+bhh)   (fp32)
//   Phase 2 (R9): ONE persistent kernel (plain launch) for the 32 recurrence
//            steps, fenceless LLC group barrier (R7/R8: 5.25 us/step).
//            R9 changes (elementwise phase was scalar + store-heavy):
//              - thread -> (row=tid>>3, 4 contiguous u cols): gx/gbuf reads
//                become float4, H publish becomes ONE 8B sc0sc1 store per
//                thread (was 4 scattered 2B LLC RMWs).
//              - C and S live in REGISTERS (the (chain,u) a thread owns is
//                step-invariant) -> zero C/S global traffic, memset 3MB->1MB.
//              - gbuf stride 33->36 so float4 reads are 16B-aligned.
//   Phase 3: out = Apack @ Wout^T + bout -> [3968][7680] fp32
//            128x128 LDS-tiled MFMA GEMM w/ global_load_lds + XOR-swizzled
//            LDS chunks; R9 adds bijective XCD-aware block swizzle (T1).

#define BT __hip_bfloat16

typedef short bf16x8 __attribute__((ext_vector_type(8)));
typedef float f32x4 __attribute__((ext_vector_type(4)));

__device__ __forceinline__ bf16x8 ld_frag(const BT* p) {
    return *reinterpret_cast<const bf16x8*>(p);
}
__device__ __forceinline__ f32x4 mfma16(bf16x8 a, bf16x8 b, f32x4 c) {
    return __builtin_amdgcn_mfma_f32_16x16x32_bf16(a, b, c, 0, 0, 0);
}
__device__ __forceinline__ float sigm(float x) { return 1.0f / (1.0f + __expf(-x)); }
// NaN-safe fast tanh: tanh(x) = sign(x) * (1-e)/(1+e), e = exp(-2|x|)
__device__ __forceinline__ float tanhfast(float x) {
    float e = __expf(-2.0f * fabsf(x));
    float r = (1.0f - e) / (1.0f + e);
    return copysignf(r, x);
}

// ---- system-scope (LLC-coherent) accessors: bypass L1+L2, no fences ----
__device__ __forceinline__ bf16x8 ld_sys16(const BT* p) {
    bf16x8 r;
    asm volatile("global_load_dwordx4 %0, %1, off sc0 sc1"
                 : "=v"(r) : "v"(p) : "memory");
    return r;
}
__device__ __forceinline__ void st_sys_u64(void* p, unsigned long long v) {
    asm volatile("global_store_dwordx2 %0, %1, off sc0 sc1"
                 :: "v"(p), "v"(v) : "memory");
}
__device__ __forceinline__ void st_sys_u32(unsigned int* p, unsigned int v) {
    asm volatile("global_store_dword %0, %1, off sc0 sc1"
                 :: "v"(p), "v"(v) : "memory");
}
__device__ __forceinline__ unsigned int ld_sys_u32(const unsigned int* p) {
    unsigned int r;
    asm volatile("global_load_dword %0, %1, off sc0 sc1\n\t"
                 "s_waitcnt vmcnt(0)"
                 : "=v"(r) : "v"(p) : "memory");
    return r;
}

// async 16B global -> LDS (wave-uniform LDS base + lane*16 hardware placement)
__device__ __forceinline__ void async16(const BT* g, BT* l) {
    __builtin_amdgcn_global_load_lds(
        (const __attribute__((address_space(1))) unsigned int*)g,
        (__attribute__((address_space(3))) unsigned int*)l,
        16, 0, 0);
}

union B4 { BT b[4]; unsigned long long u; };
union F4 { float4 v; float f[4]; };

// ---------------- Phase 0: weight conversion (z=0..4) + gather (z=5) ------
__global__ __launch_bounds__(256) void prep_kernel(
    const float* __restrict__ s0, const float* __restrict__ s1,
    const float* __restrict__ s2, const float* __restrict__ s3,
    const float* __restrict__ s4, BT* __restrict__ dbase,
    const int* __restrict__ x, const float* __restrict__ emb,
    BT* __restrict__ Xemb)
{
    const int z = blockIdx.z;
    if (z == 5) {   // gather+convert embeddings: 256 rows x 128 chunks
        const int i = blockIdx.x * 256 + threadIdx.x;
        if (i < 32768) {
            const int r = i >> 7;
            const int cq = i & 127;
            const long row = x[r];
            float4 v = reinterpret_cast<const float4*>(emb + row * 512)[cq];
            B4 t;
            t.b[0] = __float2bfloat16(v.x); t.b[1] = __float2bfloat16(v.y);
            t.b[2] = __float2bfloat16(v.z); t.b[3] = __float2bfloat16(v.w);
            reinterpret_cast<unsigned long long*>(Xemb + (long)r * 512)[cq] = t.u;
        }
        return;
    }
    const float* src = (z == 0) ? s0 : (z == 1) ? s1 : (z == 2) ? s2 : (z == 3) ? s3 : s4;
    const int nel = (z == 4) ? 7864320 : 1048576;
    BT* dst = dbase + (long)z * 1048576;
    const int n4 = nel >> 2;
    for (int i = blockIdx.x * 256 + threadIdx.x; i < n4; i += gridDim.x * 256) {
        float4 v = reinterpret_cast<const float4*>(src)[i];
        B4 t;
        t.b[0] = __float2bfloat16(v.x); t.b[1] = __float2bfloat16(v.y);
        t.b[2] = __float2bfloat16(v.z); t.b[3] = __float2bfloat16(v.w);
        reinterpret_cast<unsigned long long*>(dst)[i] = t.u;
    }
}

// ---------------- Phase 1: x-gates (also inits rec flags at LLC) ----------
__global__ __launch_bounds__(256) void gx_kernel(
    const BT* __restrict__ Xemb,
    const BT* __restrict__ WihF, const BT* __restrict__ WihB,
    const float* __restrict__ bih_f, const float* __restrict__ bhh_f,
    const float* __restrict__ bih_b, const float* __restrict__ bhh_b,
    float* __restrict__ Gx, unsigned int* __restrict__ flags)
{
    const int dir = blockIdx.z;
    const BT* Wih = dir ? WihB : WihF;
    const float* bih = dir ? bih_b : bih_f;
    const float* bhh = dir ? bhh_b : bhh_f;
    float* G = Gx + (long)dir * 256 * 2048;

    const int tid = threadIdx.x;
    const int w = tid >> 6, lane = tid & 63;
    const int m = lane & 15, q = lane >> 4;
    const int r0 = blockIdx.x * 32;
    const int c0 = blockIdx.y * 128 + w * 32;

    if (tid == 0)   // write-through so rec's sc0sc1 polls can't see stale LLC
        st_sys_u32(&flags[(blockIdx.z * 8 + blockIdx.x) * 16 + blockIdx.y], 0u);

    const BT* a0p = Xemb + (long)(r0 + m) * 512 + q * 8;
    const BT* a1p = Xemb + (long)(r0 + 16 + m) * 512 + q * 8;
    const BT* b0p = Wih + (long)(c0 + m) * 512 + q * 8;
    const BT* b1p = Wih + (long)(c0 + 16 + m) * 512 + q * 8;

    f32x4 acc[2][2] = {};
    for (int k0 = 0; k0 < 512; k0 += 32) {
        bf16x8 a0 = ld_frag(a0p + k0);
        bf16x8 a1 = ld_frag(a1p + k0);
        bf16x8 b0 = ld_frag(b0p + k0);
        bf16x8 b1 = ld_frag(b1p + k0);
        acc[0][0] = mfma16(a0, b0, acc[0][0]);
        acc[0][1] = mfma16(a0, b1, acc[0][1]);
        acc[1][0] = mfma16(a1, b0, acc[1][0]);
        acc[1][1] = mfma16(a1, b1, acc[1][1]);
    }
    #pragma unroll
    for (int rt = 0; rt < 2; ++rt)
        #pragma unroll
        for (int ct = 0; ct < 2; ++ct)
            #pragma unroll
            for (int reg = 0; reg < 4; ++reg) {
                int r = r0 + rt * 16 + q * 4 + reg;
                int c = c0 + ct * 16 + m;
                G[(long)r * 2048 + c] = acc[rt][ct][reg] + bih[c] + bhh[c];
            }
}

// ---------------- Phase 2: persistent recurrence, fenceless barriers ------
// grid (8,16,2) = 256 blocks (1 per CU), 256 threads (4 waves).
// Block (x,y,dir) owns chain rows x*32..+31 and gate-col slice y*32..+31
// (wave g handles gate g). Group = 16 blocks sharing (x,dir). Per step:
//   stage Hi rows (32 KB, LLC) into XOR-swizzled LDS -> MFMA -> gbuf ->
//   cell update (C in regs) -> ONE 8B write-through H store per thread ->
//   vmcnt(0) -> flag++ -> [S-prefix/Apack (S in regs) hides partner latency]
//   -> spin on 16 flags. No threadfence, no L2 flushes.
__global__ __launch_bounds__(256, 1) void rec_kernel(
    const BT* __restrict__ WhhF, const BT* __restrict__ WhhB,
    const float* __restrict__ Gx,
    BT* __restrict__ H0, BT* __restrict__ H1,
    BT* __restrict__ Apack, unsigned int* __restrict__ flags)
{
    const int dir = blockIdx.z;
    const int tid = threadIdx.x;
    const int w = tid >> 6, lane = tid & 63;
    const int m = lane & 15, q = lane >> 4;

    const BT* W = dir ? WhhB : WhhF;
    const float* G = Gx + (long)dir * 256 * 2048;
    BT* Ha = H0 + (long)dir * 256 * 512;
    BT* Hb = H1 + (long)dir * 256 * 512;

    const int r0 = blockIdx.x * 32;
    const int u0 = blockIdx.y * 32;
    unsigned int* flg = flags + (dir * 8 + blockIdx.x) * 16;
    const int myy = blockIdx.y;

    // hoist Whh fragments (constant across all 32 steps)
    const BT* b0p = W + (long)(w * 512 + u0 + m) * 512 + q * 8;
    const BT* b1p = W + (long)(w * 512 + u0 + 16 + m) * 512 + q * 8;
    bf16x8 wb0[16], wb1[16];
    #pragma unroll
    for (int kk = 0; kk < 16; ++kk) {
        wb0[kk] = ld_frag(b0p + kk * 32);
        wb1[kk] = ld_frag(b1p + kk * 32);
    }

    __shared__ float gbuf[4][32][36];       // stride 36: float4 reads aligned
    __shared__ BT hbuf[32 * 512];           // 32 KB staged H tile (swizzled)

    const int srow = tid >> 3;              // 0..31 staging row
    const int sch0 = tid & 7;               // base chunk (of 64 8-elem chunks)
    const int xr = m & 7;                   // read-side XOR key

    // elementwise mapping: thread owns row er, 4 contiguous cols eu4..eu4+3
    // (step-invariant -> C and S live in registers)
    const int er = tid >> 3;                // 0..31
    const int eu4 = (tid & 7) * 4;          // 0,4,...,28
    const int echain = r0 + er;
    const int ed = echain >> 3, eb = echain & 7;
    const int eu = u0 + eu4;
    float creg[4] = {}, sreg[4] = {};

    for (int s = 0; s < 32; ++s) {
        const BT* Hi = (s & 1) ? Hb : Ha;
        BT* Ho = (s & 1) ? Ha : Hb;
        const bool active = (r0 < 8 * (s + 1));
        const bool ework = active && (ed <= s);
        const int pos = dir ? (31 - s) : s;

        if (active) {
            // ---- stage Hi rows r0..r0+31 (LLC-coherent) into swizzled LDS ----
            const BT* hsrc = Hi + (long)(r0 + srow) * 512;
            bf16x8 hv[8];
            #pragma unroll
            for (int rr = 0; rr < 8; ++rr)
                hv[rr] = ld_sys16(hsrc + (sch0 + rr * 8) * 8);
            asm volatile("s_waitcnt vmcnt(0)" ::: "memory");
            __builtin_amdgcn_sched_barrier(0);
            #pragma unroll
            for (int rr = 0; rr < 8; ++rr) {
                const int ch = sch0 + rr * 8;
                *reinterpret_cast<bf16x8*>(
                    hbuf + srow * 512 + (ch ^ (srow & 7)) * 8) = hv[rr];
            }
            __syncthreads();

            // ---- gate GEMM: gbuf = Hi @ Whh_slice^T ----
            f32x4 acc[2][2] = {};
            #pragma unroll
            for (int kk = 0; kk < 16; ++kk) {
                const int sl = (((kk << 2) | q) ^ xr) * 8;
                bf16x8 a0 = *reinterpret_cast<const bf16x8*>(hbuf + m * 512 + sl);
                bf16x8 a1 = *reinterpret_cast<const bf16x8*>(hbuf + (16 + m) * 512 + sl);
                acc[0][0] = mfma16(a0, wb0[kk], acc[0][0]);
                acc[0][1] = mfma16(a0, wb1[kk], acc[0][1]);
                acc[1][0] = mfma16(a1, wb0[kk], acc[1][0]);
                acc[1][1] = mfma16(a1, wb1[kk], acc[1][1]);
            }
            #pragma unroll
            for (int rt = 0; rt < 2; ++rt)
                #pragma unroll
                for (int ct = 0; ct < 2; ++ct)
                    #pragma unroll
                    for (int reg = 0; reg < 4; ++reg)
                        gbuf[w][rt * 16 + q * 4 + reg][ct * 16 + m] = acc[rt][ct][reg];
            __syncthreads();

            // ---- pass 1: cell update (C in regs), publish h (8B store) ----
            if (ework) {
                const float* gxp = G + (long)(eb * 32 + pos) * 2048 + eu;
                F4 xi, xf, xg, xo, hi4, hf4, hg4, ho4;
                xi.v = *(const float4*)(gxp);
                xf.v = *(const float4*)(gxp + 512);
                xg.v = *(const float4*)(gxp + 1024);
                xo.v = *(const float4*)(gxp + 1536);
                hi4.v = *(const float4*)&gbuf[0][er][eu4];
                hf4.v = *(const float4*)&gbuf[1][er][eu4];
                hg4.v = *(const float4*)&gbuf[2][er][eu4];
                ho4.v = *(const float4*)&gbuf[3][er][eu4];
                B4 hp;
                #pragma unroll
                for (int jj = 0; jj < 4; ++jj) {
                    const float gi = hi4.f[jj] + xi.f[jj];
                    const float gf = hf4.f[jj] + xf.f[jj];
                    const float gg = hg4.f[jj] + xg.f[jj];
                    const float go = ho4.f[jj] + xo.f[jj];
                    const float c_new = sigm(gf) * creg[jj] + sigm(gi) * tanhfast(gg);
                    const float h = sigm(go) * tanhfast(c_new);
                    creg[jj] = c_new;
                    sreg[jj] += h;
                    hp.b[jj] = __float2bfloat16(h);
                }
                st_sys_u64(Ho + (long)echain * 512 + eu, hp.u);
            }
        }

        // ---- signal as early as possible (H already at LLC) ----
        if (s < 31) {
            asm volatile("s_waitcnt vmcnt(0)" ::: "memory");  // drain H stores
            __syncthreads();                                  // all waves done
            if (tid == 0)
                st_sys_u32(&flg[myy], (unsigned)(s + 1));
        }

        // ---- pass 2: span-mean pack (hidden by partner poll latency) ----
        if (ework) {
            const int k = s - ed;
            if (k >= 1) {
                const float inv = __builtin_amdgcn_rcpf((float)(k + 1));
                B4 ap;
                #pragma unroll
                for (int jj = 0; jj < 4; ++jj)
                    ap.b[jj] = __float2bfloat16(sreg[jj] * inv);
                const int p_span = dir ? pos : ed;
                const int off = (k - 1) * 32 - ((k - 1) * k) / 2;
                *reinterpret_cast<unsigned long long*>(
                    Apack + (long)(eb * 496 + off + p_span) * 1024 + dir * 512 + eu) = ap.u;
            }
        }

        // ---- wait for 16 partners ----
        if (s < 31) {
            if (tid < 16) {
                const unsigned int tgt = (unsigned)(s + 1);
                while (ld_sys_u32(&flg[tid]) < tgt)
                    __builtin_amdgcn_s_sleep(1);
            }
            __syncthreads();
            asm volatile("" ::: "memory");   // no reordering across barrier
        }
    }
}

// ---------------- Phase 3: projection ----------------
// C[3968][7680] = Apack[3968][1024] @ Wout[7680][1024]^T + bout.
// grid (31, 60), block 256 = 4 waves (2x2 of 64x64); tile 128x128, BK=64.
// LDS tiles stored row-major [row][64] with XOR chunk swizzle.
// R9: bijective XCD-aware block swizzle (nwg=1860 = 8*232 + 4).
__global__ __launch_bounds__(256) void proj_kernel(
    const BT* __restrict__ Apack, const BT* __restrict__ Woutbf,
    const float* __restrict__ bout, float* __restrict__ out)
{
    __shared__ BT As[128 * 64];
    __shared__ BT Bs[128 * 64];

    const int tid = threadIdx.x;
    const int lane = tid & 63;
    const int wu = __builtin_amdgcn_readfirstlane(tid >> 6);
    const int m = lane & 15, q = lane >> 4;
    const int wr = wu >> 1, wc = wu & 1;

    // bijective XCD swizzle: consecutive remapped ids land on one XCD
    int id = blockIdx.x + 31 * blockIdx.y;
    const int qq = 232, rr = 4;            // 1860 = 8*232 + 4
    const int xcd = id & 7, rank = id >> 3;
    id = (xcd < rr) ? (xcd * (qq + 1) + rank)
                    : (rr * (qq + 1) + (xcd - rr) * qq + rank);
    const int r0 = (id % 31) * 128;
    const int c0 = (id / 31) * 128;

    const int srow = lane >> 3;             // 0..7 within 8-row staging group
    const int schunk = (lane & 7) ^ srow;   // swizzled global chunk index

    f32x4 acc[4][4] = {};

    for (int kc = 0; kc < 16; ++kc) {
        const int k0 = kc * 64;
        #pragma unroll
        for (int j = 0; j < 4; ++j) {
            const int L = wu * 4 + j;           // 0..15 staging group
            const int row = L * 8 + srow;       // 0..127 tile row
            async16(Apack + (long)(r0 + row) * 1024 + k0 + schunk * 8,
                    As + L * 512);
            async16(Woutbf + (long)(c0 + row) * 1024 + k0 + schunk * 8,
                    Bs + L * 512);
        }
        __syncthreads();
        #pragma unroll
        for (int ks = 0; ks < 2; ++ks) {
            const int slot = ((ks << 2) | q) ^ (m & 7);
            bf16x8 af[4], bf[4];
            #pragma unroll
            for (int t = 0; t < 4; ++t) {
                af[t] = ld_frag(As + (wr * 64 + t * 16 + m) * 64 + slot * 8);
                bf[t] = ld_frag(Bs + (wc * 64 + t * 16 + m) * 64 + slot * 8);
            }
            #pragma unroll
            for (int mt = 0; mt < 4; ++mt)
                #pragma unroll
                for (int nt = 0; nt < 4; ++nt)
                    acc[mt][nt] = mfma16(af[mt], bf[nt], acc[mt][nt]);
        }
        __syncthreads();
    }

    #pragma unroll
    for (int mt = 0; mt < 4; ++mt)
        #pragma unroll
        for (int nt = 0; nt < 4; ++nt)
            #pragma unroll
            for (int reg = 0; reg < 4; ++reg) {
                const int r = r0 + wr * 64 + mt * 16 + q * 4 + reg;
                const int c = c0 + wc * 64 + nt * 16 + m;
                out[(long)r * 7680 + c] = acc[mt][nt][reg] + bout[c];
            }
}

extern "C" void kernel_launch(void* const* d_in, const int* in_sizes, int n_in,
                              void* d_out, int out_size, void* d_ws, size_t ws_size,
                              hipStream_t stream) {
    const int*   x     = (const int*)d_in[0];
    const float* emb   = (const float*)d_in[2];
    const float* Wih_f = (const float*)d_in[3];
    const float* Whh_f = (const float*)d_in[4];
    const float* bih_f = (const float*)d_in[5];
    const float* bhh_f = (const float*)d_in[6];
    const float* Wih_b = (const float*)d_in[7];
    const float* Whh_b = (const float*)d_in[8];
    const float* bih_b = (const float*)d_in[9];
    const float* bhh_b = (const float*)d_in[10];
    const float* Wout  = (const float*)d_in[11];
    const float* bout  = (const float*)d_in[12];
    float* out = (float*)d_out;

    char* ws = (char*)d_ws;
    const long MB = 1 << 20;
    float* Gx    = (float*)(ws + 0);              // 4 MiB
    BT*    H0    = (BT*)(ws + 4 * MB);            // 512 KiB
    BT*    H1    = (BT*)(ws + 4 * MB + 512 * 1024);
    BT*    Apack = (BT*)(ws + 7 * MB);            // 7.75 MiB
    BT*    Xemb  = (BT*)(ws + 7 * MB + 7936 * 1024);  // 256 KiB
    BT*    Wbf   = (BT*)(ws + 15 * MB);           // 23 MiB -> ends at 38 MiB
    BT*    WihF  = Wbf;
    BT*    WihB  = Wbf + 1048576;
    BT*    WhhF  = Wbf + 2 * 1048576;
    BT*    WhhB  = Wbf + 3 * 1048576;
    BT*    Woutb = Wbf + 4 * 1048576;
    unsigned int* flags = (unsigned int*)(ws + 38 * MB);  // 1 KiB (16 grp x 16)

    hipMemsetAsync(ws + 4 * MB, 0, 1 * MB, stream);   // H0 + H1 only

    prep_kernel<<<dim3(512, 1, 6), 256, 0, stream>>>(
        Wih_f, Wih_b, Whh_f, Whh_b, Wout, Wbf, x, emb, Xemb);

    gx_kernel<<<dim3(8, 16, 2), 256, 0, stream>>>(
        Xemb, WihF, WihB, bih_f, bhh_f, bih_b, bhh_b, Gx, flags);

    // Plain launch: 256 blocks x 4 waves = 1024 waves << 8192 slots; all
    // blocks resident regardless of placement -> spin barrier is safe.
    rec_kernel<<<dim3(8, 16, 2), 256, 0, stream>>>(
        WhhF, WhhB, Gx, H0, H1, Apack, flags);

    proj_kernel<<<dim3(31, 60), 256, 0, stream>>>(Apack, Woutb, bout, out);
}